// Round 13
// baseline (30837.344 us; speedup 1.0000x reference)
//
#include <hip/hip_runtime.h>

typedef unsigned short u16;
typedef __attribute__((ext_vector_type(8))) short short8;
typedef __attribute__((ext_vector_type(4))) float f32x4;

#define NB 256      // batch
#define TE 512      // encoder T
#define DK 256      // key dim
#define DV 256      // value dim
#define HH 512      // hidden
#define NV 35       // vocab
#define STEPS 300
#define TLEN 301
#define K1 1280     // LSTM1 inner dim: emb(512) + ctx(256) + h1(512)
#define K2 768      // LSTM2 inner dim: h1(512) + h2(256)
#define NBLK 256

__device__ __forceinline__ float bf2f(u16 u){ return __uint_as_float(((unsigned)u)<<16); }
__device__ __forceinline__ u16 f2bf(float f){
  unsigned u = __float_as_uint(f);
  u += 0x7fffu + ((u>>16)&1u);   // RNE
  return (u16)(u>>16);
}
__device__ __forceinline__ void splitbf(float f, short& hi, short& lo){
  u16 h = f2bf(f);
  float r = f - bf2f(h);
  hi = (short)h; lo = (short)f2bf(r);
}
__device__ __forceinline__ float sigm(float x){ return 1.f/(1.f+expf(-x)); }

// Hierarchical grid barrier, RELAXED polls (no per-poll L2 invalidate — the
// R9/R10 ACQUIRE-poll versions invalidated L2 on every spin iteration).
// Fences only at edges: release threadfence before arrive (wbL2), one acquire
// threadfence after the condition is observed (invL2) — the edge-fence
// protocol R9 proved numerically correct.
__device__ __forceinline__ void gbar(unsigned* cnt, int b, unsigned round){
  __syncthreads();
  if (threadIdx.x == 0){
    __threadfence();
    unsigned* g    = cnt + (b&7)*64;     // per-XCD line (round-robin dispatch)
    unsigned* root = cnt + 8*64;
    __hip_atomic_fetch_add(g, 1u, __ATOMIC_RELAXED, __HIP_MEMORY_SCOPE_AGENT);
    if (b < 8){   // one leader per XCD group
      while (__hip_atomic_load(g, __ATOMIC_RELAXED, __HIP_MEMORY_SCOPE_AGENT) < round*32u)
        __builtin_amdgcn_s_sleep(1);
      __hip_atomic_fetch_add(root, 1u, __ATOMIC_RELAXED, __HIP_MEMORY_SCOPE_AGENT);
    }
    while (__hip_atomic_load(root, __ATOMIC_RELAXED, __HIP_MEMORY_SCOPE_AGENT) < round*8u)
      __builtin_amdgcn_s_sleep(1);
    __threadfence();
  }
  __syncthreads();
}

// ---------------- conversion kernel (once per launch) ----------------
__global__ void conv_cat_split(u16* __restrict__ dhi, u16* __restrict__ dlo,
                               const float* __restrict__ s1, const float* __restrict__ s2,
                               int k1, int k2, int total8){
  int i = blockIdx.x*blockDim.x + threadIdx.x;
  if (i >= total8) return;
  int ktot = k1 + k2;
  long e = (long)i*8;
  int r = (int)(e / ktot); int k = (int)(e - (long)r*ktot);
  const float* s = (k < k1) ? (s1 + (size_t)r*k1 + k) : (s2 + (size_t)r*k2 + (k-k1));
  short8 oh, ol;
  #pragma unroll
  for (int q=0;q<8;++q){ short h,l; splitbf(s[q],h,l); oh[q]=h; ol[q]=l; }
  *(short8*)(dhi + e) = oh;
  *(short8*)(dlo + e) = ol;
}

__device__ __forceinline__ void split8r(const float* x, short8& vh, short8& vl){
  #pragma unroll
  for (int q=0;q<8;++q){ short h,l; splitbf(x[q],h,l); vh[q]=h; vl[q]=l; }
}

struct Params {
  const float *enc_key, *enc_val;
  const int *text, *lens;
  const float *emb;
  const u16 *W1h, *W1l, *W2h, *W2l;
  const float *bi1, *bh1, *bi2, *bh2;
  const float *Wout, *bout;
  float *h1b, *h2b, *ctx, *out;
  unsigned *cnt;
};

// ============ persistent cooperative kernel: all 300 steps ============
// 256 blocks x 512 thr (8 waves). Phases: lstm1 (K-split 8-wave GEMM),
// lstm2 (blocks<128), attn (block = batch row). 3 relaxed-poll barriers/step.
__global__ __launch_bounds__(512, 1) void decoder_k(Params P)
{
  __shared__ __align__(16) float accS[4][4][2][64][4];   // 32 KB GEMM reduce
  __shared__ float h2s[DK];
  __shared__ float e_s[TE];
  __shared__ float ctx_s[DV];
  __shared__ float ctxp[8][DV];
  __shared__ float red_s[16];

  const int b = blockIdx.x, tid = threadIdx.x;
  const int w = tid>>6, l = tid&63;
  const int nh = w&1, kq = w>>1;
  const int col = l&15, kc = l>>4, ofs = kc*8;
  const int en = tid>>4, ej = tid&15;
  const int nhe = en>>4, er = en&15;
  const int lane_e = ((er>>2)<<4) | ej, reg_e = er&3;

  const int jt1  = (b&7)*4 + ((b>>3)&3);
  const int jh0_1 = jt1*16;
  const int n0_1  = (b>>5)*32;
  const int jt2  = (b&7)*2 + ((b>>3)&1);
  const int jh0_2 = jt2*16;
  const int n0_2  = (b>>4)*32;
  const bool p2act = b < 128;

  // biases hoisted (per epilogue cell)
  float b1i = P.bi1[jh0_1+ej]      + P.bh1[jh0_1+ej];
  float b1f = P.bi1[HH+jh0_1+ej]   + P.bh1[HH+jh0_1+ej];
  float b1g = P.bi1[2*HH+jh0_1+ej] + P.bh1[2*HH+jh0_1+ej];
  float b1o = P.bi1[3*HH+jh0_1+ej] + P.bh1[3*HH+jh0_1+ej];
  float b2i=0.f,b2f=0.f,b2g=0.f,b2o=0.f;
  if (p2act){
    b2i = P.bi2[jh0_2+ej]      + P.bh2[jh0_2+ej];
    b2f = P.bi2[DK+jh0_2+ej]   + P.bh2[DK+jh0_2+ej];
    b2g = P.bi2[2*DK+jh0_2+ej] + P.bh2[2*DK+jh0_2+ej];
    b2o = P.bi2[3*DK+jh0_2+ej] + P.bh2[3*DK+jh0_2+ej];
  }
  // weight pointers (constant over steps)
  const int kb1 = kq*(K1/4), kb2 = kq*(K2/4);
  const u16 *pB1h[4], *pB1l[4], *pB2h[4], *pB2l[4];
  #pragma unroll
  for (int g=0; g<4; ++g){
    size_t r1 = (size_t)(g*512 + jh0_1 + col)*K1 + kb1 + ofs;
    pB1h[g] = P.W1h + r1; pB1l[g] = P.W1l + r1;
    size_t r2 = (size_t)(g*256 + jh0_2 + col)*K2 + kb2 + ofs;
    pB2h[g] = P.W2h + r2; pB2l[g] = P.W2l + r2;
  }

  float c1r = 0.f, c2r = 0.f;       // cell state in registers (1 cell/thread)
  unsigned round = 0;

  for (int t=0; t<STEPS; ++t){
    const int par = t&1;
    const float* h1_old = P.h1b + (size_t)par*NB*HH;
    float*       h1_new = P.h1b + (size_t)(par^1)*NB*HH;
    const float* h2_old = P.h2b + (size_t)par*NB*DK;
    float*       h2_new = P.h2b + (size_t)(par^1)*NB*DK;

    // ===================== phase 1: LSTM1 (K-split 8-wave) =====================
    {
      int arow = n0_1 + nh*16 + col;
      const float* aemb = P.emb + (size_t)P.text[arow*TLEN + t]*HH;
      const float* actx = P.ctx + (size_t)arow*DV;
      const float* ah1  = h1_old + (size_t)arow*HH;

      f32x4 acc[4];
      #pragma unroll
      for (int g=0;g<4;++g) acc[g] = (f32x4){0.f,0.f,0.f,0.f};

      float xs[8]; short8 rbh[4], rbl[4];
      {
        int k = kb1;
        const float* src = (k<512)? (aemb+k) : (k<768)? (actx+(k-512)) : (ah1+(k-768));
        *(float4*)&xs[0] = *(const float4*)(src + ofs);
        *(float4*)&xs[4] = *(const float4*)(src + ofs + 4);
        #pragma unroll
        for (int g=0;g<4;++g){ rbh[g] = *(const short8*)(pB1h[g]); rbl[g] = *(const short8*)(pB1l[g]); }
      }
      for (int k0=0; k0<K1/4; k0+=32){
        float cxs[8];
        #pragma unroll
        for (int q=0;q<8;++q) cxs[q] = xs[q];
        short8 cbh[4], cbl[4];
        #pragma unroll
        for (int g=0;g<4;++g){ cbh[g]=rbh[g]; cbl[g]=rbl[g]; }
        int k0n = k0 + 32;
        if (k0n < K1/4){
          int k = kb1 + k0n;
          const float* src = (k<512)? (aemb+k) : (k<768)? (actx+(k-512)) : (ah1+(k-768));
          *(float4*)&xs[0] = *(const float4*)(src + ofs);
          *(float4*)&xs[4] = *(const float4*)(src + ofs + 4);
          #pragma unroll
          for (int g=0;g<4;++g){ rbh[g] = *(const short8*)(pB1h[g] + k0n); rbl[g] = *(const short8*)(pB1l[g] + k0n); }
        }
        short8 avh, avl;
        split8r(cxs, avh, avl);
        #pragma unroll
        for (int g=0; g<4; ++g){
          acc[g] = __builtin_amdgcn_mfma_f32_16x16x32_bf16(avh, cbh[g], acc[g], 0,0,0);
          acc[g] = __builtin_amdgcn_mfma_f32_16x16x32_bf16(avl, cbh[g], acc[g], 0,0,0);
          acc[g] = __builtin_amdgcn_mfma_f32_16x16x32_bf16(avh, cbl[g], acc[g], 0,0,0);
        }
      }
      #pragma unroll
      for (int g=0;g<4;++g) *(f32x4*)&accS[g][kq][nh][l][0] = acc[g];
      __syncthreads();
      {
        float gv4[4];
        #pragma unroll
        for (int g=0;g<4;++g){
          gv4[g] = accS[g][0][nhe][lane_e][reg_e] + accS[g][1][nhe][lane_e][reg_e]
                 + accS[g][2][nhe][lane_e][reg_e] + accS[g][3][nhe][lane_e][reg_e];
        }
        float iv = sigm(gv4[0]+b1i);
        float fv = sigm(gv4[1]+b1f);
        float gg = tanhf(gv4[2]+b1g);
        float ov = sigm(gv4[3]+b1o);
        float cn = fv*c1r + iv*gg;
        c1r = cn;
        h1_new[(size_t)(n0_1+en)*HH + jh0_1+ej] = ov*tanhf(cn);
      }
    }
    ++round; gbar(P.cnt, b, round);

    // ===================== phase 2: LSTM2 (blocks < 128) =====================
    if (p2act){
      int arow = n0_2 + nh*16 + col;
      const float* ah1 = h1_new + (size_t)arow*HH;
      const float* ah2 = h2_old + (size_t)arow*DK;

      f32x4 acc[4];
      #pragma unroll
      for (int g=0;g<4;++g) acc[g] = (f32x4){0.f,0.f,0.f,0.f};

      float xs[8]; short8 rbh[4], rbl[4];
      {
        int k = kb2;
        const float* src = (k<512)? (ah1+k) : (ah2+(k-512));
        *(float4*)&xs[0] = *(const float4*)(src + ofs);
        *(float4*)&xs[4] = *(const float4*)(src + ofs + 4);
        #pragma unroll
        for (int g=0;g<4;++g){ rbh[g] = *(const short8*)(pB2h[g]); rbl[g] = *(const short8*)(pB2l[g]); }
      }
      for (int k0=0; k0<K2/4; k0+=32){
        float cxs[8];
        #pragma unroll
        for (int q=0;q<8;++q) cxs[q] = xs[q];
        short8 cbh[4], cbl[4];
        #pragma unroll
        for (int g=0;g<4;++g){ cbh[g]=rbh[g]; cbl[g]=rbl[g]; }
        int k0n = k0 + 32;
        if (k0n < K2/4){
          int k = kb2 + k0n;
          const float* src = (k<512)? (ah1+k) : (ah2+(k-512));
          *(float4*)&xs[0] = *(const float4*)(src + ofs);
          *(float4*)&xs[4] = *(const float4*)(src + ofs + 4);
          #pragma unroll
          for (int g=0;g<4;++g){ rbh[g] = *(const short8*)(pB2h[g] + k0n); rbl[g] = *(const short8*)(pB2l[g] + k0n); }
        }
        short8 avh, avl;
        split8r(cxs, avh, avl);
        #pragma unroll
        for (int g=0; g<4; ++g){
          acc[g] = __builtin_amdgcn_mfma_f32_16x16x32_bf16(avh, cbh[g], acc[g], 0,0,0);
          acc[g] = __builtin_amdgcn_mfma_f32_16x16x32_bf16(avl, cbh[g], acc[g], 0,0,0);
          acc[g] = __builtin_amdgcn_mfma_f32_16x16x32_bf16(avh, cbl[g], acc[g], 0,0,0);
        }
      }
      #pragma unroll
      for (int g=0;g<4;++g) *(f32x4*)&accS[g][kq][nh][l][0] = acc[g];
      __syncthreads();
      {
        float gv4[4];
        #pragma unroll
        for (int g=0;g<4;++g){
          gv4[g] = accS[g][0][nhe][lane_e][reg_e] + accS[g][1][nhe][lane_e][reg_e]
                 + accS[g][2][nhe][lane_e][reg_e] + accS[g][3][nhe][lane_e][reg_e];
        }
        float iv = sigm(gv4[0]+b2i);
        float fv = sigm(gv4[1]+b2f);
        float gg = tanhf(gv4[2]+b2g);
        float ov = sigm(gv4[3]+b2o);
        float cn = fv*c2r + iv*gg;
        c2r = cn;
        h2_new[(size_t)(n0_2+en)*DK + jh0_2+ej] = ov*tanhf(cn);
      }
    }
    ++round; gbar(P.cnt, b, round);

    // ===================== phase 3: attention + output (row n = b) =====================
    {
      const int n = b;
      int L = P.lens[n] >> 3;
      if (tid < DK) h2s[tid] = h2_new[(size_t)n*DK + tid];
      __syncthreads();
      float qreg[32];
      {
        int off = (l&7)*32;
        #pragma unroll
        for (int q=0;q<32;q+=4){
          float4 v4 = *(const float4*)&h2s[off+q];
          qreg[q]=v4.x; qreg[q+1]=v4.y; qreg[q+2]=v4.z; qreg[q+3]=v4.w;
        }
      }
      const float* kb = P.enc_key + (size_t)n*TE*DK;
      for (int r = w*8 + (l>>3); r < L; r += 64){
        const float* kr = kb + (size_t)r*DK + (l&7)*32;
        float s = 0.f;
        #pragma unroll
        for (int q=0;q<32;q+=4){
          float4 kv = *(const float4*)(kr + q);
          s += kv.x*qreg[q] + kv.y*qreg[q+1] + kv.z*qreg[q+2] + kv.w*qreg[q+3];
        }
        s += __shfl_xor(s,1); s += __shfl_xor(s,2); s += __shfl_xor(s,4);
        if ((l&7)==0) e_s[r] = s;
      }
      __syncthreads();
      float v = (tid < L) ? e_s[tid] : -1e30f;
      float m = v;
      #pragma unroll
      for (int o=1;o<64;o<<=1) m = fmaxf(m, __shfl_xor(m,o));
      if (l==0) red_s[w] = m;
      __syncthreads();
      m = red_s[0];
      #pragma unroll
      for (int q=1;q<8;++q) m = fmaxf(m, red_s[q]);
      float p = (tid < L) ? expf(v-m) : 0.f;
      float sm = p;
      #pragma unroll
      for (int o=1;o<64;o<<=1) sm += __shfl_xor(sm,o);
      if (l==0) red_s[8+w] = sm;
      __syncthreads();
      sm = red_s[8];
      #pragma unroll
      for (int q=1;q<8;++q) sm += red_s[8+q];
      e_s[tid] = p * (1.f/sm);
      __syncthreads();
      float4 cacc = {0.f,0.f,0.f,0.f};
      const float* vpb = P.enc_val + (size_t)n*TE*DV + l*4;
      for (int r = w; r < L; r += 8){
        float a = e_s[r];
        float4 vv4 = *(const float4*)(vpb + (size_t)r*DV);
        cacc.x += a*vv4.x; cacc.y += a*vv4.y; cacc.z += a*vv4.z; cacc.w += a*vv4.w;
      }
      *(float4*)&ctxp[w][l*4] = cacc;
      __syncthreads();
      if (tid < DV){
        float cv = 0.f;
        #pragma unroll
        for (int q=0;q<8;++q) cv += ctxp[q][tid];
        ctx_s[tid] = cv;
        P.ctx[(size_t)n*DV + tid] = cv;
      }
      __syncthreads();
      #pragma unroll
      for (int vb2=0; vb2<2; ++vb2){
        int vvv = vb2*32 + (tid>>4);
        if (vvv < NV){
          int kbase = (tid&15)*32;
          float s = 0.f;
          #pragma unroll
          for (int q=0;q<32;q+=4){
            float4 w4 = *(const float4*)(P.Wout + (size_t)vvv*512 + kbase + q);
            int k = kbase + q;
            const float* xsv = (k < DK)? &h2s[k] : &ctx_s[k-DK];
            s += w4.x*xsv[0] + w4.y*xsv[1] + w4.z*xsv[2] + w4.w*xsv[3];
          }
          s += __shfl_xor(s,1); s += __shfl_xor(s,2); s += __shfl_xor(s,4); s += __shfl_xor(s,8);
          if ((tid&15)==0) P.out[((size_t)n*STEPS + t)*NV + vvv] = s + P.bout[vvv];
        }
      }
    }
    ++round; gbar(P.cnt, b, round);
  }
}

// ---------------- host ----------------
extern "C" void kernel_launch(void* const* d_in, const int* in_sizes, int n_in,
                              void* d_out, int out_size, void* d_ws, size_t ws_size,
                              hipStream_t stream)
{
  const float* enc_key = (const float*)d_in[0];
  const float* enc_val = (const float*)d_in[1];
  const int*   text    = (const int*)d_in[2];
  const int*   lens    = (const int*)d_in[3];
  const float* emb     = (const float*)d_in[5];
  const float* W_ih1   = (const float*)d_in[6];
  const float* W_hh1   = (const float*)d_in[7];
  const float* b_ih1   = (const float*)d_in[8];
  const float* b_hh1   = (const float*)d_in[9];
  const float* W_ih2   = (const float*)d_in[10];
  const float* W_hh2   = (const float*)d_in[11];
  const float* b_ih2   = (const float*)d_in[12];
  const float* b_hh2   = (const float*)d_in[13];
  const float* W_out   = (const float*)d_in[14];
  const float* b_out   = (const float*)d_in[15];
  float* out = (float*)d_out;

  char* ws = (char*)d_ws;
  size_t off = 0;
  auto alloc = [&](size_t bytes)->char*{
    char* p = ws + off; off = (off + bytes + 255) & ~(size_t)255; return p;
  };

  u16* Wc1h = (u16*)alloc((size_t)2048*K1*2);
  u16* Wc1l = (u16*)alloc((size_t)2048*K1*2);
  u16* Wc2h = (u16*)alloc((size_t)1024*K2*2);
  u16* Wc2l = (u16*)alloc((size_t)1024*K2*2);
  float* h1b = (float*)alloc((size_t)2*NB*HH*4);
  float* h2b = (float*)alloc((size_t)2*NB*DK*4);
  float* ctx = (float*)alloc((size_t)NB*DV*4);
  unsigned* cnt = (unsigned*)alloc(4096);   // 8 group lines (256B apart) + root

  // zero recurrent state + barrier counters; re-runs on every graph replay
  size_t zbytes = ((char*)cnt + 4096) - (char*)h1b;
  (void)hipMemsetAsync(h1b, 0, zbytes, stream);

  {
    int t8 = 2048*K1/8;
    conv_cat_split<<<(t8+255)/256, 256, 0, stream>>>(Wc1h, Wc1l, W_ih1, W_hh1, 768, 512, t8);
  }
  {
    int t8 = 1024*K2/8;
    conv_cat_split<<<(t8+255)/256, 256, 0, stream>>>(Wc2h, Wc2l, W_ih2, W_hh2, 512, 256, t8);
  }

  Params p;
  p.enc_key = enc_key; p.enc_val = enc_val;
  p.text = text; p.lens = lens; p.emb = emb;
  p.W1h = Wc1h; p.W1l = Wc1l; p.W2h = Wc2h; p.W2l = Wc2l;
  p.bi1 = b_ih1; p.bh1 = b_hh1; p.bi2 = b_ih2; p.bh2 = b_hh2;
  p.Wout = W_out; p.bout = b_out;
  p.h1b = h1b; p.h2b = h2b; p.ctx = ctx; p.out = out;
  p.cnt = cnt;

  void* kargs[] = { &p };
  (void)hipLaunchCooperativeKernel((void*)decoder_k, dim3(NBLK), dim3(512), kargs, 0, stream);
}

// Round 14
// 27961.630 us; speedup vs baseline: 1.1028x; 1.1028x over previous
//
#include <hip/hip_runtime.h>

typedef unsigned short u16;
typedef __attribute__((ext_vector_type(8))) short short8;
typedef __attribute__((ext_vector_type(4))) float f32x4;

#define NB 256      // batch
#define TE 512      // encoder T
#define DK 256      // key dim
#define DV 256      // value dim
#define HH 512      // hidden
#define NV 35       // vocab
#define STEPS 300
#define TLEN 301
#define K1 1280     // LSTM1 inner dim: emb(512) + ctx(256) + h1(512)
#define K2 768      // LSTM2 inner dim: h1(512) + h2(256)

__device__ __forceinline__ float bf2f(u16 u){ return __uint_as_float(((unsigned)u)<<16); }
__device__ __forceinline__ u16 f2bf(float f){
  unsigned u = __float_as_uint(f);
  u += 0x7fffu + ((u>>16)&1u);   // RNE
  return (u16)(u>>16);
}
__device__ __forceinline__ void splitbf(float f, short& hi, short& lo){
  u16 h = f2bf(f);
  float r = f - bf2f(h);
  hi = (short)h; lo = (short)f2bf(r);
}
__device__ __forceinline__ float sigm(float x){ return 1.f/(1.f+expf(-x)); }

// ---------------- conversion kernel (once per launch) ----------------
__global__ void conv_cat_split(u16* __restrict__ dhi, u16* __restrict__ dlo,
                               const float* __restrict__ s1, const float* __restrict__ s2,
                               int k1, int k2, int total8){
  int i = blockIdx.x*blockDim.x + threadIdx.x;
  if (i >= total8) return;
  int ktot = k1 + k2;
  long e = (long)i*8;
  int r = (int)(e / ktot); int k = (int)(e - (long)r*ktot);
  const float* s = (k < k1) ? (s1 + (size_t)r*k1 + k) : (s2 + (size_t)r*k2 + (k-k1));
  short8 oh, ol;
  #pragma unroll
  for (int q=0;q<8;++q){ short h,l; splitbf(s[q],h,l); oh[q]=h; ol[q]=l; }
  *(short8*)(dhi + e) = oh;
  *(short8*)(dlo + e) = ol;
}

__device__ __forceinline__ void split8r(const float* x, short8& vh, short8& vl){
  #pragma unroll
  for (int q=0;q<8;++q){ short h,l; splitbf(x[q],h,l); vh[q]=h; vl[q]=l; }
}

// ---------------- LSTM1: K-split 8-wave GEMM + cell update (R12-proven) ----------------
__global__ __launch_bounds__(512) void lstm1_k(
  const int* __restrict__ text, int t, int par,
  const float* __restrict__ emb,
  const float* __restrict__ ctx,
  float* __restrict__ h1b,
  float* __restrict__ c1,
  const u16* __restrict__ Whi, const u16* __restrict__ Wlo,
  const float* __restrict__ b_ih, const float* __restrict__ b_hh)
{
  __shared__ __align__(16) float accS[4][4][2][64][4];   // [gate][kq][nh][lane][reg] 32KB
  const float* h1_old = h1b + (size_t)par*NB*HH;
  float* h1_new = h1b + (size_t)(par^1)*NB*HH;
  int b = blockIdx.x;
  int jt  = (b&7)*4 + ((b>>3)&3);     // XCD-grouped jh tiles (W slice L2-resident)
  int jh0 = jt*16;
  int n0  = (b>>5)*32;
  int tid = threadIdx.x, w = tid>>6, l = tid&63;
  int nh = w&1, kq = w>>1;
  int kbase = kq*(K1/4);
  int col = l&15, kc = l>>4, ofs = kc*8;

  int arow = n0 + nh*16 + col;
  const float* aemb = emb + (size_t)text[arow*TLEN + t]*HH;
  const float* actx = ctx + (size_t)arow*DV;
  const float* ah1  = h1_old + (size_t)arow*HH;

  const u16* pBh[4]; const u16* pBl[4];
  #pragma unroll
  for (int g=0; g<4; ++g){
    size_t r = (size_t)(g*512 + jh0 + col)*K1 + kbase + ofs;
    pBh[g] = Whi + r; pBl[g] = Wlo + r;
  }

  f32x4 acc[4];
  #pragma unroll
  for (int g=0;g<4;++g) acc[g] = (f32x4){0.f,0.f,0.f,0.f};

  float xs[8]; short8 rbh[4], rbl[4];
  {
    int k = kbase;
    const float* src = (k<512)? (aemb+k) : (k<768)? (actx+(k-512)) : (ah1+(k-768));
    *(float4*)&xs[0] = *(const float4*)(src + ofs);
    *(float4*)&xs[4] = *(const float4*)(src + ofs + 4);
    #pragma unroll
    for (int g=0;g<4;++g){ rbh[g] = *(const short8*)(pBh[g]); rbl[g] = *(const short8*)(pBl[g]); }
  }

  for (int k0=0; k0<K1/4; k0+=32){
    float cxs[8];
    #pragma unroll
    for (int q=0;q<8;++q) cxs[q] = xs[q];
    short8 cbh[4], cbl[4];
    #pragma unroll
    for (int g=0;g<4;++g){ cbh[g]=rbh[g]; cbl[g]=rbl[g]; }
    int k0n = k0 + 32;
    if (k0n < K1/4){
      int k = kbase + k0n;
      const float* src = (k<512)? (aemb+k) : (k<768)? (actx+(k-512)) : (ah1+(k-768));
      *(float4*)&xs[0] = *(const float4*)(src + ofs);
      *(float4*)&xs[4] = *(const float4*)(src + ofs + 4);
      #pragma unroll
      for (int g=0;g<4;++g){ rbh[g] = *(const short8*)(pBh[g] + k0n); rbl[g] = *(const short8*)(pBl[g] + k0n); }
    }
    short8 avh, avl;
    split8r(cxs, avh, avl);
    #pragma unroll
    for (int g=0; g<4; ++g){
      acc[g] = __builtin_amdgcn_mfma_f32_16x16x32_bf16(avh, cbh[g], acc[g], 0,0,0);
      acc[g] = __builtin_amdgcn_mfma_f32_16x16x32_bf16(avl, cbh[g], acc[g], 0,0,0);
      acc[g] = __builtin_amdgcn_mfma_f32_16x16x32_bf16(avh, cbl[g], acc[g], 0,0,0);
    }
  }

  #pragma unroll
  for (int g=0;g<4;++g) *(f32x4*)&accS[g][kq][nh][l][0] = acc[g];
  __syncthreads();

  int en = tid>>4, ej = tid&15;
  int nhe = en>>4, r = en&15;
  int lane_e = ((r>>2)<<4) | ej, reg = r&3;
  float gv4[4];
  #pragma unroll
  for (int g=0;g<4;++g){
    gv4[g] = accS[g][0][nhe][lane_e][reg] + accS[g][1][nhe][lane_e][reg]
           + accS[g][2][nhe][lane_e][reg] + accS[g][3][nhe][lane_e][reg];
  }
  int jh = jh0 + ej;
  float bi  = b_ih[jh]      + b_hh[jh];
  float bff = b_ih[HH+jh]   + b_hh[HH+jh];
  float bg  = b_ih[2*HH+jh] + b_hh[2*HH+jh];
  float bo  = b_ih[3*HH+jh] + b_hh[3*HH+jh];
  size_t idx = (size_t)(n0+en)*HH + jh;
  float iv = sigm(gv4[0]+bi);
  float fv = sigm(gv4[1]+bff);
  float gg = tanhf(gv4[2]+bg);
  float ov = sigm(gv4[3]+bo);
  float cn = fv*c1[idx] + iv*gg;
  c1[idx] = cn;
  h1_new[idx] = ov*tanhf(cn);
}

// ---------------- LSTM2: K-split 8-wave, K=768 (R12-proven) ----------------
__global__ __launch_bounds__(512) void lstm2_k(
  int par,
  const float* __restrict__ h1b,
  float* __restrict__ h2b,
  float* __restrict__ c2,
  const u16* __restrict__ Whi, const u16* __restrict__ Wlo,
  const float* __restrict__ b_ih, const float* __restrict__ b_hh)
{
  __shared__ __align__(16) float accS[4][4][2][64][4];
  const float* h1_cur = h1b + (size_t)(par^1)*NB*HH;
  const float* h2_old = h2b + (size_t)par*NB*DK;
  float* h2_new = h2b + (size_t)(par^1)*NB*DK;
  int b = blockIdx.x;
  int jt  = (b&7)*2 + ((b>>3)&1);
  int jh0 = jt*16;
  int n0  = (b>>4)*32;
  int tid = threadIdx.x, w = tid>>6, l = tid&63;
  int nh = w&1, kq = w>>1;
  int kbase = kq*(K2/4);
  int col = l&15, kc = l>>4, ofs = kc*8;

  int arow = n0 + nh*16 + col;
  const float* ah1 = h1_cur + (size_t)arow*HH;
  const float* ah2 = h2_old + (size_t)arow*DK;

  const u16* pBh[4]; const u16* pBl[4];
  #pragma unroll
  for (int g=0; g<4; ++g){
    size_t r = (size_t)(g*256 + jh0 + col)*K2 + kbase + ofs;
    pBh[g] = Whi + r; pBl[g] = Wlo + r;
  }

  f32x4 acc[4];
  #pragma unroll
  for (int g=0;g<4;++g) acc[g] = (f32x4){0.f,0.f,0.f,0.f};

  float xs[8]; short8 rbh[4], rbl[4];
  {
    int k = kbase;
    const float* src = (k<512)? (ah1+k) : (ah2+(k-512));
    *(float4*)&xs[0] = *(const float4*)(src + ofs);
    *(float4*)&xs[4] = *(const float4*)(src + ofs + 4);
    #pragma unroll
    for (int g=0;g<4;++g){ rbh[g] = *(const short8*)(pBh[g]); rbl[g] = *(const short8*)(pBl[g]); }
  }

  for (int k0=0; k0<K2/4; k0+=32){
    float cxs[8];
    #pragma unroll
    for (int q=0;q<8;++q) cxs[q] = xs[q];
    short8 cbh[4], cbl[4];
    #pragma unroll
    for (int g=0;g<4;++g){ cbh[g]=rbh[g]; cbl[g]=rbl[g]; }
    int k0n = k0 + 32;
    if (k0n < K2/4){
      int k = kbase + k0n;
      const float* src = (k<512)? (ah1+k) : (ah2+(k-512));
      *(float4*)&xs[0] = *(const float4*)(src + ofs);
      *(float4*)&xs[4] = *(const float4*)(src + ofs + 4);
      #pragma unroll
      for (int g=0;g<4;++g){ rbh[g] = *(const short8*)(pBh[g] + k0n); rbl[g] = *(const short8*)(pBl[g] + k0n); }
    }
    short8 avh, avl;
    split8r(cxs, avh, avl);
    #pragma unroll
    for (int g=0; g<4; ++g){
      acc[g] = __builtin_amdgcn_mfma_f32_16x16x32_bf16(avh, cbh[g], acc[g], 0,0,0);
      acc[g] = __builtin_amdgcn_mfma_f32_16x16x32_bf16(avl, cbh[g], acc[g], 0,0,0);
      acc[g] = __builtin_amdgcn_mfma_f32_16x16x32_bf16(avh, cbl[g], acc[g], 0,0,0);
    }
  }

  #pragma unroll
  for (int g=0;g<4;++g) *(f32x4*)&accS[g][kq][nh][l][0] = acc[g];
  __syncthreads();

  int en = tid>>4, ej = tid&15;
  int nhe = en>>4, r = en&15;
  int lane_e = ((r>>2)<<4) | ej, reg = r&3;
  float gv4[4];
  #pragma unroll
  for (int g=0;g<4;++g){
    gv4[g] = accS[g][0][nhe][lane_e][reg] + accS[g][1][nhe][lane_e][reg]
           + accS[g][2][nhe][lane_e][reg] + accS[g][3][nhe][lane_e][reg];
  }
  int jh = jh0 + ej;
  float bi  = b_ih[jh]      + b_hh[jh];
  float bff = b_ih[DK+jh]   + b_hh[DK+jh];
  float bg  = b_ih[2*DK+jh] + b_hh[2*DK+jh];
  float bo  = b_ih[3*DK+jh] + b_hh[3*DK+jh];
  size_t idx = (size_t)(n0+en)*DK + jh;
  float iv = sigm(gv4[0]+bi);
  float fv = sigm(gv4[1]+bff);
  float gg = tanhf(gv4[2]+bg);
  float ov = sigm(gv4[3]+bo);
  float cn = fv*c2[idx] + iv*gg;
  c2[idx] = cn;
  h2_new[idx] = ov*tanhf(cn);
}

// ---------------- pair-split attention: 512 blocks, 2 per row ----------------
// Block n (consumer) does t in [0, ceil(L/2)); block n+256 (producer) does the
// rest. Both run online softmax (m, l, unnormalized o). Producer publishes
// partials via release flag (value t+1, monotonic); consumer combines exactly,
// writes ctx + output. Halves the straggler (max-L row) time per step.
__global__ __launch_bounds__(256) void attn_k(
  const float* __restrict__ keys, const float* __restrict__ vals,
  const int* __restrict__ lens,
  const float* __restrict__ h2b, int par,
  float* __restrict__ ctx,
  const float* __restrict__ Wout, const float* __restrict__ b_out,
  float* __restrict__ out, int t,
  float* __restrict__ pwork, unsigned* __restrict__ pflag)
{
  __shared__ float h2s[DK];
  __shared__ float e_s[TE];
  __shared__ float red_s[8];
  __shared__ float op[4][DV];
  __shared__ float ctx_s[DV];
  int bb = blockIdx.x, tid = threadIdx.x;
  int wv = tid>>6, lane = tid&63;
  bool prod = bb >= NB;
  int n = prod ? bb - NB : bb;
  int L = lens[n] >> 3;
  int half = (L+1) >> 1;
  int lo = prod ? half : 0;
  int hi = prod ? L : half;
  int cnt = hi - lo;                 // <= 256
  h2s[tid] = h2b[(size_t)(par^1)*NB*DK + (size_t)n*DK + tid];
  __syncthreads();
  float qreg[32];
  int off = (lane&7)*32;
  #pragma unroll
  for (int q=0;q<32;q+=4){
    float4 v4 = *(const float4*)&h2s[off+q];
    qreg[q]=v4.x; qreg[q+1]=v4.y; qreg[q+2]=v4.z; qreg[q+3]=v4.w;
  }
  // QK over [lo,hi): 8 lanes/row, 32 rows per sweep (4 waves)
  const float* kb = keys + (size_t)n*TE*DK;
  for (int r = lo + wv*8 + (lane>>3); r < hi; r += 32){
    const float* kr = kb + (size_t)r*DK + off;
    float s = 0.f;
    #pragma unroll
    for (int q=0;q<32;q+=4){
      float4 kv = *(const float4*)(kr + q);
      s += kv.x*qreg[q] + kv.y*qreg[q+1] + kv.z*qreg[q+2] + kv.w*qreg[q+3];
    }
    s += __shfl_xor(s,1); s += __shfl_xor(s,2); s += __shfl_xor(s,4);
    if ((lane&7)==0) e_s[r] = s;
  }
  __syncthreads();
  // local softmax stats over my range (one element per thread)
  float v = (tid < cnt) ? e_s[lo+tid] : -1e30f;
  float m = v;
  #pragma unroll
  for (int o=1;o<64;o<<=1) m = fmaxf(m, __shfl_xor(m,o));
  if (lane==0) red_s[wv] = m;
  __syncthreads();
  m = fmaxf(fmaxf(red_s[0],red_s[1]), fmaxf(red_s[2],red_s[3]));
  float p = (tid < cnt) ? expf(v-m) : 0.f;
  float l = p;
  #pragma unroll
  for (int o=1;o<64;o<<=1) l += __shfl_xor(l,o);
  if (lane==0) red_s[4+wv] = l;
  __syncthreads();
  l = red_s[4]+red_s[5]+red_s[6]+red_s[7];
  if (tid < cnt) e_s[lo+tid] = p;       // unnormalized weights at scale m
  __syncthreads();
  // PV over [lo,hi): wave-strided rows, lane owns 4 dims
  float4 cacc = {0.f,0.f,0.f,0.f};
  const float* vpb = vals + (size_t)n*TE*DV + lane*4;
  for (int r = lo+wv; r < hi; r += 4){
    float a = e_s[r];
    float4 vv4 = *(const float4*)(vpb + (size_t)r*DV);
    cacc.x += a*vv4.x; cacc.y += a*vv4.y; cacc.z += a*vv4.z; cacc.w += a*vv4.w;
  }
  *(float4*)&op[wv][lane*4] = cacc;
  __syncthreads();
  float o_l = op[0][tid]+op[1][tid]+op[2][tid]+op[3][tid];   // unnormalized o

  float* pw = pwork + (size_t)n*260;
  if (prod){
    pw[tid] = o_l;
    if (tid==0){ pw[256]=m; pw[257]=l; }
    __syncthreads();
    if (tid==0){
      __threadfence();   // release: flush partials to coherence point
      __hip_atomic_store(pflag+n, (unsigned)(t+1), __ATOMIC_RELAXED, __HIP_MEMORY_SCOPE_AGENT);
    }
  } else {
    if (tid==0){
      while (__hip_atomic_load(pflag+n, __ATOMIC_RELAXED, __HIP_MEMORY_SCOPE_AGENT) < (unsigned)(t+1))
        __builtin_amdgcn_s_sleep(1);
      __threadfence();   // acquire: invalidate stale lines before reading partials
    }
    __syncthreads();
    float o_p = pw[tid];
    float mp = pw[256], lp = pw[257];
    float M = fmaxf(m, mp);
    float wc = expf(m - M), wp = expf(mp - M);
    float denom = l*wc + lp*wp;
    float cv = (o_l*wc + o_p*wp) / denom;
    ctx_s[tid] = cv;
    ctx[(size_t)n*DV + tid] = cv;
    __syncthreads();
    // output projection: 8 lanes per vocab row, 2 passes over 64 vocab slots
    #pragma unroll
    for (int vb2=0; vb2<2; ++vb2){
      int vv = vb2*32 + (tid>>3);
      if (vv < NV){
        int kp = (tid&7)*64;
        float s = 0.f;
        #pragma unroll
        for (int d=0; d<64; d+=4){
          float4 w4 = *(const float4*)(Wout + (size_t)vv*512 + kp + d);
          int k = kp+d;
          float x0 = (k<DK)?   h2s[k]   : ctx_s[k-DK];
          float x1 = (k+1<DK)? h2s[k+1] : ctx_s[k+1-DK];
          float x2 = (k+2<DK)? h2s[k+2] : ctx_s[k+2-DK];
          float x3 = (k+3<DK)? h2s[k+3] : ctx_s[k+3-DK];
          s += w4.x*x0 + w4.y*x1 + w4.z*x2 + w4.w*x3;
        }
        s += __shfl_xor(s,1); s += __shfl_xor(s,2); s += __shfl_xor(s,4);
        if ((tid&7)==0) out[((size_t)n*STEPS + t)*NV + vv] = s + b_out[vv];
      }
    }
  }
}

// ---------------- host ----------------
extern "C" void kernel_launch(void* const* d_in, const int* in_sizes, int n_in,
                              void* d_out, int out_size, void* d_ws, size_t ws_size,
                              hipStream_t stream)
{
  const float* enc_key = (const float*)d_in[0];
  const float* enc_val = (const float*)d_in[1];
  const int*   text    = (const int*)d_in[2];
  const int*   lens    = (const int*)d_in[3];
  const float* emb     = (const float*)d_in[5];
  const float* W_ih1   = (const float*)d_in[6];
  const float* W_hh1   = (const float*)d_in[7];
  const float* b_ih1   = (const float*)d_in[8];
  const float* b_hh1   = (const float*)d_in[9];
  const float* W_ih2   = (const float*)d_in[10];
  const float* W_hh2   = (const float*)d_in[11];
  const float* b_ih2   = (const float*)d_in[12];
  const float* b_hh2   = (const float*)d_in[13];
  const float* W_out   = (const float*)d_in[14];
  const float* b_out   = (const float*)d_in[15];
  float* out = (float*)d_out;

  char* ws = (char*)d_ws;
  size_t off = 0;
  auto alloc = [&](size_t bytes)->char*{
    char* p = ws + off; off = (off + bytes + 255) & ~(size_t)255; return p;
  };

  u16* Wc1h = (u16*)alloc((size_t)2048*K1*2);
  u16* Wc1l = (u16*)alloc((size_t)2048*K1*2);
  u16* Wc2h = (u16*)alloc((size_t)1024*K2*2);
  u16* Wc2l = (u16*)alloc((size_t)1024*K2*2);
  float* h1b = (float*)alloc((size_t)2*NB*HH*4);
  float* h2b = (float*)alloc((size_t)2*NB*DK*4);
  float* ctx = (float*)alloc((size_t)NB*DV*4);
  float* c1  = (float*)alloc((size_t)NB*HH*4);
  float* c2  = (float*)alloc((size_t)NB*DK*4);
  unsigned* pflag = (unsigned*)alloc((size_t)NB*4);
  float* pwork = (float*)alloc((size_t)NB*260*4);

  // zero recurrent state + flags (contiguous h1b..pflag); re-runs each replay
  size_t zbytes = ((char*)pflag + (size_t)NB*4) - (char*)h1b;
  (void)hipMemsetAsync(h1b, 0, zbytes, stream);

  {
    int t8 = 2048*K1/8;
    conv_cat_split<<<(t8+255)/256, 256, 0, stream>>>(Wc1h, Wc1l, W_ih1, W_hh1, 768, 512, t8);
  }
  {
    int t8 = 1024*K2/8;
    conv_cat_split<<<(t8+255)/256, 256, 0, stream>>>(Wc2h, Wc2l, W_ih2, W_hh2, 512, 256, t8);
  }

  for (int t=0; t<STEPS; ++t){
    int par = t&1;
    lstm1_k<<<256, 512, 0, stream>>>(text, t, par, emb, ctx, h1b, c1, Wc1h, Wc1l, b_ih1, b_hh1);
    lstm2_k<<<128, 512, 0, stream>>>(par, h1b, h2b, c2, Wc2h, Wc2l, b_ih2, b_hh2);
    attn_k<<<512, 256, 0, stream>>>(enc_key, enc_val, lens, h2b, par, ctx, W_out, b_out, out, t,
                                    pwork, pflag);
  }
}

// Round 15
// 26295.575 us; speedup vs baseline: 1.1727x; 1.0634x over previous
//
#include <hip/hip_runtime.h>

typedef unsigned short u16;
typedef __attribute__((ext_vector_type(8))) short short8;
typedef __attribute__((ext_vector_type(4))) float f32x4;

#define NB 256      // batch
#define TE 512      // encoder T
#define DK 256      // key dim
#define DV 256      // value dim
#define HH 512      // hidden
#define NV 35       // vocab
#define STEPS 300
#define TLEN 301
#define K1 1280     // LSTM1 inner dim: emb(512) + ctx(256) + h1(512)
#define K2 768      // LSTM2 inner dim: h1(512) + h2(256)

__device__ __forceinline__ float bf2f(u16 u){ return __uint_as_float(((unsigned)u)<<16); }
__device__ __forceinline__ u16 f2bf(float f){
  unsigned u = __float_as_uint(f);
  u += 0x7fffu + ((u>>16)&1u);   // RNE
  return (u16)(u>>16);
}
__device__ __forceinline__ void splitbf(float f, short& hi, short& lo){
  u16 h = f2bf(f);
  float r = f - bf2f(h);
  hi = (short)h; lo = (short)f2bf(r);
}
__device__ __forceinline__ float sigm(float x){ return 1.f/(1.f+expf(-x)); }

// ---------------- conversion kernel (once per launch) ----------------
__global__ void conv_cat_split(u16* __restrict__ dhi, u16* __restrict__ dlo,
                               const float* __restrict__ s1, const float* __restrict__ s2,
                               int k1, int k2, int total8){
  int i = blockIdx.x*blockDim.x + threadIdx.x;
  if (i >= total8) return;
  int ktot = k1 + k2;
  long e = (long)i*8;
  int r = (int)(e / ktot); int k = (int)(e - (long)r*ktot);
  const float* s = (k < k1) ? (s1 + (size_t)r*k1 + k) : (s2 + (size_t)r*k2 + (k-k1));
  short8 oh, ol;
  #pragma unroll
  for (int q=0;q<8;++q){ short h,l; splitbf(s[q],h,l); oh[q]=h; ol[q]=l; }
  *(short8*)(dhi + e) = oh;
  *(short8*)(dlo + e) = ol;
}

__device__ __forceinline__ void split8r(const float* x, short8& vh, short8& vl){
  #pragma unroll
  for (int q=0;q<8;++q){ short h,l; splitbf(x[q],h,l); vh[q]=h; vl[q]=l; }
}

// ---------------- LSTM1: K-split 8-wave GEMM + cell update (R12-proven) ----------------
__global__ __launch_bounds__(512) void lstm1_k(
  const int* __restrict__ text, int t, int par,
  const float* __restrict__ emb,
  const float* __restrict__ ctx,
  float* __restrict__ h1b,
  float* __restrict__ c1,
  const u16* __restrict__ Whi, const u16* __restrict__ Wlo,
  const float* __restrict__ b_ih, const float* __restrict__ b_hh)
{
  __shared__ __align__(16) float accS[4][4][2][64][4];   // [gate][kq][nh][lane][reg] 32KB
  const float* h1_old = h1b + (size_t)par*NB*HH;
  float* h1_new = h1b + (size_t)(par^1)*NB*HH;
  int b = blockIdx.x;
  int jt  = (b&7)*4 + ((b>>3)&3);     // XCD-grouped jh tiles (W slice L2-resident)
  int jh0 = jt*16;
  int n0  = (b>>5)*32;
  int tid = threadIdx.x, w = tid>>6, l = tid&63;
  int nh = w&1, kq = w>>1;
  int kbase = kq*(K1/4);
  int col = l&15, kc = l>>4, ofs = kc*8;

  int arow = n0 + nh*16 + col;
  const float* aemb = emb + (size_t)text[arow*TLEN + t]*HH;
  const float* actx = ctx + (size_t)arow*DV;
  const float* ah1  = h1_old + (size_t)arow*HH;

  const u16* pBh[4]; const u16* pBl[4];
  #pragma unroll
  for (int g=0; g<4; ++g){
    size_t r = (size_t)(g*512 + jh0 + col)*K1 + kbase + ofs;
    pBh[g] = Whi + r; pBl[g] = Wlo + r;
  }

  f32x4 acc[4];
  #pragma unroll
  for (int g=0;g<4;++g) acc[g] = (f32x4){0.f,0.f,0.f,0.f};

  float xs[8]; short8 rbh[4], rbl[4];
  {
    int k = kbase;
    const float* src = (k<512)? (aemb+k) : (k<768)? (actx+(k-512)) : (ah1+(k-768));
    *(float4*)&xs[0] = *(const float4*)(src + ofs);
    *(float4*)&xs[4] = *(const float4*)(src + ofs + 4);
    #pragma unroll
    for (int g=0;g<4;++g){ rbh[g] = *(const short8*)(pBh[g]); rbl[g] = *(const short8*)(pBl[g]); }
  }

  for (int k0=0; k0<K1/4; k0+=32){
    float cxs[8];
    #pragma unroll
    for (int q=0;q<8;++q) cxs[q] = xs[q];
    short8 cbh[4], cbl[4];
    #pragma unroll
    for (int g=0;g<4;++g){ cbh[g]=rbh[g]; cbl[g]=rbl[g]; }
    int k0n = k0 + 32;
    if (k0n < K1/4){
      int k = kbase + k0n;
      const float* src = (k<512)? (aemb+k) : (k<768)? (actx+(k-512)) : (ah1+(k-768));
      *(float4*)&xs[0] = *(const float4*)(src + ofs);
      *(float4*)&xs[4] = *(const float4*)(src + ofs + 4);
      #pragma unroll
      for (int g=0;g<4;++g){ rbh[g] = *(const short8*)(pBh[g] + k0n); rbl[g] = *(const short8*)(pBl[g] + k0n); }
    }
    short8 avh, avl;
    split8r(cxs, avh, avl);
    #pragma unroll
    for (int g=0; g<4; ++g){
      acc[g] = __builtin_amdgcn_mfma_f32_16x16x32_bf16(avh, cbh[g], acc[g], 0,0,0);
      acc[g] = __builtin_amdgcn_mfma_f32_16x16x32_bf16(avl, cbh[g], acc[g], 0,0,0);
      acc[g] = __builtin_amdgcn_mfma_f32_16x16x32_bf16(avh, cbl[g], acc[g], 0,0,0);
    }
  }

  #pragma unroll
  for (int g=0;g<4;++g) *(f32x4*)&accS[g][kq][nh][l][0] = acc[g];
  __syncthreads();

  int en = tid>>4, ej = tid&15;
  int nhe = en>>4, r = en&15;
  int lane_e = ((r>>2)<<4) | ej, reg = r&3;
  float gv4[4];
  #pragma unroll
  for (int g=0;g<4;++g){
    gv4[g] = accS[g][0][nhe][lane_e][reg] + accS[g][1][nhe][lane_e][reg]
           + accS[g][2][nhe][lane_e][reg] + accS[g][3][nhe][lane_e][reg];
  }
  int jh = jh0 + ej;
  float bi  = b_ih[jh]      + b_hh[jh];
  float bff = b_ih[HH+jh]   + b_hh[HH+jh];
  float bg  = b_ih[2*HH+jh] + b_hh[2*HH+jh];
  float bo  = b_ih[3*HH+jh] + b_hh[3*HH+jh];
  size_t idx = (size_t)(n0+en)*HH + jh;
  float iv = sigm(gv4[0]+bi);
  float fv = sigm(gv4[1]+bff);
  float gg = tanhf(gv4[2]+bg);
  float ov = sigm(gv4[3]+bo);
  float cn = fv*c1[idx] + iv*gg;
  c1[idx] = cn;
  h1_new[idx] = ov*tanhf(cn);
}

// ---------------- fused2: lstm2 (blocks 0..127) + attn (blocks 128..383) ----------------
// Producers release per-n-tile monotonic counters (16 jh-tile blocks each);
// consumers acquire before reading h2_new. launch_bounds(512,4) caps VGPR so
// 2 blocks/CU are guaranteed resident -> 384 blocks co-resident, no deadlock.
__global__ __launch_bounds__(512, 4) void fused2_k(
  int par, int t,
  const float* __restrict__ h1b,
  float* __restrict__ h2b,
  float* __restrict__ c2,
  const u16* __restrict__ Whi, const u16* __restrict__ Wlo,
  const float* __restrict__ b_ih, const float* __restrict__ b_hh,
  const float* __restrict__ keys, const float* __restrict__ vals,
  const int* __restrict__ lens,
  float* __restrict__ ctx,
  const float* __restrict__ Wout, const float* __restrict__ b_out,
  float* __restrict__ out,
  unsigned* __restrict__ cnt2)
{
  __shared__ __align__(16) float accS[4][4][2][64][4];   // lstm2 reduce (32KB)
  __shared__ float h2s[DK];
  __shared__ float e_s[TE];
  __shared__ float ctx_s[DV];
  __shared__ float ctxp[8][DV];
  __shared__ float red_s[16];

  int bb = blockIdx.x, tid = threadIdx.x;
  const float* h1_cur = h1b + (size_t)(par^1)*NB*HH;
  float* h2_new = h2b + (size_t)(par^1)*NB*DK;

  if (bb < 128){
    // ======== lstm2 (R12-proven body) ========
    const float* h2_old = h2b + (size_t)par*NB*DK;
    int b = bb;
    int jt  = (b&7)*2 + ((b>>3)&1);
    int jh0 = jt*16;
    int n0  = (b>>4)*32;
    int w = tid>>6, l = tid&63;
    int nh = w&1, kq = w>>1;
    int kbase = kq*(K2/4);
    int col = l&15, kc = l>>4, ofs = kc*8;

    int arow = n0 + nh*16 + col;
    const float* ah1 = h1_cur + (size_t)arow*HH;
    const float* ah2 = h2_old + (size_t)arow*DK;

    const u16* pBh[4]; const u16* pBl[4];
    #pragma unroll
    for (int g=0; g<4; ++g){
      size_t r = (size_t)(g*256 + jh0 + col)*K2 + kbase + ofs;
      pBh[g] = Whi + r; pBl[g] = Wlo + r;
    }

    f32x4 acc[4];
    #pragma unroll
    for (int g=0;g<4;++g) acc[g] = (f32x4){0.f,0.f,0.f,0.f};

    float xs[8]; short8 rbh[4], rbl[4];
    {
      int k = kbase;
      const float* src = (k<512)? (ah1+k) : (ah2+(k-512));
      *(float4*)&xs[0] = *(const float4*)(src + ofs);
      *(float4*)&xs[4] = *(const float4*)(src + ofs + 4);
      #pragma unroll
      for (int g=0;g<4;++g){ rbh[g] = *(const short8*)(pBh[g]); rbl[g] = *(const short8*)(pBl[g]); }
    }

    for (int k0=0; k0<K2/4; k0+=32){
      float cxs[8];
      #pragma unroll
      for (int q=0;q<8;++q) cxs[q] = xs[q];
      short8 cbh[4], cbl[4];
      #pragma unroll
      for (int g=0;g<4;++g){ cbh[g]=rbh[g]; cbl[g]=rbl[g]; }
      int k0n = k0 + 32;
      if (k0n < K2/4){
        int k = kbase + k0n;
        const float* src = (k<512)? (ah1+k) : (ah2+(k-512));
        *(float4*)&xs[0] = *(const float4*)(src + ofs);
        *(float4*)&xs[4] = *(const float4*)(src + ofs + 4);
        #pragma unroll
        for (int g=0;g<4;++g){ rbh[g] = *(const short8*)(pBh[g] + k0n); rbl[g] = *(const short8*)(pBl[g] + k0n); }
      }
      short8 avh, avl;
      split8r(cxs, avh, avl);
      #pragma unroll
      for (int g=0; g<4; ++g){
        acc[g] = __builtin_amdgcn_mfma_f32_16x16x32_bf16(avh, cbh[g], acc[g], 0,0,0);
        acc[g] = __builtin_amdgcn_mfma_f32_16x16x32_bf16(avl, cbh[g], acc[g], 0,0,0);
        acc[g] = __builtin_amdgcn_mfma_f32_16x16x32_bf16(avh, cbl[g], acc[g], 0,0,0);
      }
    }

    #pragma unroll
    for (int g=0;g<4;++g) *(f32x4*)&accS[g][kq][nh][l][0] = acc[g];
    __syncthreads();

    int en = tid>>4, ej = tid&15;
    int nhe = en>>4, r = en&15;
    int lane_e = ((r>>2)<<4) | ej, reg = r&3;
    float gv4[4];
    #pragma unroll
    for (int g=0;g<4;++g){
      gv4[g] = accS[g][0][nhe][lane_e][reg] + accS[g][1][nhe][lane_e][reg]
             + accS[g][2][nhe][lane_e][reg] + accS[g][3][nhe][lane_e][reg];
    }
    int jh = jh0 + ej;
    float bi  = b_ih[jh]      + b_hh[jh];
    float bff = b_ih[DK+jh]   + b_hh[DK+jh];
    float bg  = b_ih[2*DK+jh] + b_hh[2*DK+jh];
    float bo  = b_ih[3*DK+jh] + b_hh[3*DK+jh];
    size_t idx = (size_t)(n0+en)*DK + jh;
    float iv = sigm(gv4[0]+bi);
    float fv = sigm(gv4[1]+bff);
    float gg = tanhf(gv4[2]+bg);
    float ov = sigm(gv4[3]+bo);
    float cn = fv*c2[idx] + iv*gg;
    c2[idx] = cn;
    h2_new[idx] = ov*tanhf(cn);
    __syncthreads();                   // all block stores drained (-> L2)
    if (tid == 0){
      __threadfence();                 // release: write back to coherence point
      __hip_atomic_fetch_add(cnt2 + (b>>4)*64, 1u, __ATOMIC_RELAXED, __HIP_MEMORY_SCOPE_AGENT);
    }
  } else {
    // ======== attn (R12-proven body) for row n = bb-128 ========
    int n = bb - 128;
    if (tid == 0){
      unsigned* f = cnt2 + (n>>5)*64;
      unsigned tgt = 16u*(unsigned)(t+1);
      while (__hip_atomic_load(f, __ATOMIC_RELAXED, __HIP_MEMORY_SCOPE_AGENT) < tgt)
        __builtin_amdgcn_s_sleep(1);
      __threadfence();                 // acquire: invalidate stale lines
    }
    __syncthreads();

    int wv = tid>>6, lane = tid&63;
    int L = lens[n] >> 3;
    if (tid < DK) h2s[tid] = h2_new[(size_t)n*DK + tid];
    __syncthreads();
    float qreg[32];
    {
      int off = (lane&7)*32;
      #pragma unroll
      for (int q=0;q<32;q+=4){
        float4 v4 = *(const float4*)&h2s[off+q];
        qreg[q]=v4.x; qreg[q+1]=v4.y; qreg[q+2]=v4.z; qreg[q+3]=v4.w;
      }
    }
    const float* kb = keys + (size_t)n*TE*DK;
    for (int r = wv*8 + (lane>>3); r < L; r += 64){
      const float* kr = kb + (size_t)r*DK + (lane&7)*32;
      float s = 0.f;
      #pragma unroll
      for (int q=0;q<32;q+=4){
        float4 kv = *(const float4*)(kr + q);
        s += kv.x*qreg[q] + kv.y*qreg[q+1] + kv.z*qreg[q+2] + kv.w*qreg[q+3];
      }
      s += __shfl_xor(s,1); s += __shfl_xor(s,2); s += __shfl_xor(s,4);
      if ((lane&7)==0) e_s[r] = s;
    }
    __syncthreads();
    float v = (tid < L) ? e_s[tid] : -1e30f;
    float m = v;
    #pragma unroll
    for (int o=1;o<64;o<<=1) m = fmaxf(m, __shfl_xor(m,o));
    if (lane==0) red_s[wv] = m;
    __syncthreads();
    m = red_s[0];
    #pragma unroll
    for (int q=1;q<8;++q) m = fmaxf(m, red_s[q]);
    float p = (tid < L) ? expf(v-m) : 0.f;
    float sm = p;
    #pragma unroll
    for (int o=1;o<64;o<<=1) sm += __shfl_xor(sm,o);
    if (lane==0) red_s[8+wv] = sm;
    __syncthreads();
    sm = red_s[8];
    #pragma unroll
    for (int q=1;q<8;++q) sm += red_s[8+q];
    e_s[tid] = p * (1.f/sm);
    __syncthreads();
    float4 cacc = {0.f,0.f,0.f,0.f};
    const float* vpb = vals + (size_t)n*TE*DV + lane*4;
    for (int r = wv; r < L; r += 8){
      float a = e_s[r];
      float4 vv4 = *(const float4*)(vpb + (size_t)r*DV);
      cacc.x += a*vv4.x; cacc.y += a*vv4.y; cacc.z += a*vv4.z; cacc.w += a*vv4.w;
    }
    *(float4*)&ctxp[wv][lane*4] = cacc;
    __syncthreads();
    if (tid < DV){
      float cv = 0.f;
      #pragma unroll
      for (int q=0;q<8;++q) cv += ctxp[q][tid];
      ctx_s[tid] = cv;
      ctx[(size_t)n*DV + tid] = cv;
    }
    __syncthreads();
    #pragma unroll
    for (int vb2=0; vb2<2; ++vb2){
      int vvv = vb2*32 + (tid>>4);
      if (vvv < NV){
        int kbase2 = (tid&15)*32;
        float s = 0.f;
        #pragma unroll
        for (int q=0;q<32;q+=4){
          float4 w4 = *(const float4*)(Wout + (size_t)vvv*512 + kbase2 + q);
          int k = kbase2 + q;
          const float* xsv = (k < DK)? &h2s[k] : &ctx_s[k-DK];
          s += w4.x*xsv[0] + w4.y*xsv[1] + w4.z*xsv[2] + w4.w*xsv[3];
        }
        s += __shfl_xor(s,1); s += __shfl_xor(s,2); s += __shfl_xor(s,4); s += __shfl_xor(s,8);
        if ((tid&15)==0) out[((size_t)n*STEPS + t)*NV + vvv] = s + b_out[vvv];
      }
    }
  }
}

// ---------------- host ----------------
extern "C" void kernel_launch(void* const* d_in, const int* in_sizes, int n_in,
                              void* d_out, int out_size, void* d_ws, size_t ws_size,
                              hipStream_t stream)
{
  const float* enc_key = (const float*)d_in[0];
  const float* enc_val = (const float*)d_in[1];
  const int*   text    = (const int*)d_in[2];
  const int*   lens    = (const int*)d_in[3];
  const float* emb     = (const float*)d_in[5];
  const float* W_ih1   = (const float*)d_in[6];
  const float* W_hh1   = (const float*)d_in[7];
  const float* b_ih1   = (const float*)d_in[8];
  const float* b_hh1   = (const float*)d_in[9];
  const float* W_ih2   = (const float*)d_in[10];
  const float* W_hh2   = (const float*)d_in[11];
  const float* b_ih2   = (const float*)d_in[12];
  const float* b_hh2   = (const float*)d_in[13];
  const float* W_out   = (const float*)d_in[14];
  const float* b_out   = (const float*)d_in[15];
  float* out = (float*)d_out;

  char* ws = (char*)d_ws;
  size_t off = 0;
  auto alloc = [&](size_t bytes)->char*{
    char* p = ws + off; off = (off + bytes + 255) & ~(size_t)255; return p;
  };

  u16* Wc1h = (u16*)alloc((size_t)2048*K1*2);
  u16* Wc1l = (u16*)alloc((size_t)2048*K1*2);
  u16* Wc2h = (u16*)alloc((size_t)1024*K2*2);
  u16* Wc2l = (u16*)alloc((size_t)1024*K2*2);
  float* h1b = (float*)alloc((size_t)2*NB*HH*4);
  float* h2b = (float*)alloc((size_t)2*NB*DK*4);
  float* ctx = (float*)alloc((size_t)NB*DV*4);
  float* c1  = (float*)alloc((size_t)NB*HH*4);
  float* c2  = (float*)alloc((size_t)NB*DK*4);
  unsigned* cnt2 = (unsigned*)alloc(8*256);   // 8 n-tile counters, 256B apart

  // zero recurrent state + counters (contiguous h1b..cnt2); re-runs each replay
  size_t zbytes = ((char*)cnt2 + 8*256) - (char*)h1b;
  (void)hipMemsetAsync(h1b, 0, zbytes, stream);

  {
    int t8 = 2048*K1/8;
    conv_cat_split<<<(t8+255)/256, 256, 0, stream>>>(Wc1h, Wc1l, W_ih1, W_hh1, 768, 512, t8);
  }
  {
    int t8 = 1024*K2/8;
    conv_cat_split<<<(t8+255)/256, 256, 0, stream>>>(Wc2h, Wc2l, W_ih2, W_hh2, 512, 256, t8);
  }

  for (int t=0; t<STEPS; ++t){
    int par = t&1;
    lstm1_k<<<256, 512, 0, stream>>>(text, t, par, emb, ctx, h1b, c1, Wc1h, Wc1l, b_ih1, b_hh1);
    fused2_k<<<384, 512, 0, stream>>>(par, t, h1b, h2b, c2, Wc2h, Wc2l, b_ih2, b_hh2,
                                      enc_key, enc_val, lens, ctx, W_out, b_out, out, cnt2);
  }
}

// Round 16
// 21414.140 us; speedup vs baseline: 1.4400x; 1.2280x over previous
//
#include <hip/hip_runtime.h>

typedef unsigned short u16;
typedef __attribute__((ext_vector_type(8))) short short8;
typedef __attribute__((ext_vector_type(4))) float f32x4;
typedef __attribute__((ext_vector_type(8))) _Float16 h16x8;
typedef __attribute__((ext_vector_type(4))) _Float16 h16x4;

#define NB 256      // batch
#define TE 512      // encoder T
#define DK 256      // key dim
#define DV 256      // value dim
#define HH 512      // hidden
#define NV 35       // vocab
#define STEPS 300
#define TLEN 301
#define K1 1280     // LSTM1 inner dim: emb(512) + ctx(256) + h1(512)
#define K2 768      // LSTM2 inner dim: h1(512) + h2(256)

__device__ __forceinline__ float bf2f(u16 u){ return __uint_as_float(((unsigned)u)<<16); }
__device__ __forceinline__ u16 f2bf(float f){
  unsigned u = __float_as_uint(f);
  u += 0x7fffu + ((u>>16)&1u);   // RNE
  return (u16)(u>>16);
}
__device__ __forceinline__ void splitbf(float f, short& hi, short& lo){
  u16 h = f2bf(f);
  float r = f - bf2f(h);
  hi = (short)h; lo = (short)f2bf(r);
}
__device__ __forceinline__ float sigm(float x){ return 1.f/(1.f+expf(-x)); }

// ---------------- conversion kernels (once per launch) ----------------
__global__ void conv_cat_split(u16* __restrict__ dhi, u16* __restrict__ dlo,
                               const float* __restrict__ s1, const float* __restrict__ s2,
                               int k1, int k2, int total8){
  int i = blockIdx.x*blockDim.x + threadIdx.x;
  if (i >= total8) return;
  int ktot = k1 + k2;
  long e = (long)i*8;
  int r = (int)(e / ktot); int k = (int)(e - (long)r*ktot);
  const float* s = (k < k1) ? (s1 + (size_t)r*k1 + k) : (s2 + (size_t)r*k2 + (k-k1));
  short8 oh, ol;
  #pragma unroll
  for (int q=0;q<8;++q){ short h,l; splitbf(s[q],h,l); oh[q]=h; ol[q]=l; }
  *(short8*)(dhi + e) = oh;
  *(short8*)(dlo + e) = ol;
}

// f32 -> f16 (RNE via hardware cvt)
__global__ void conv_f16(u16* __restrict__ dst, const float* __restrict__ src, int n8){
  int i = blockIdx.x*blockDim.x + threadIdx.x;
  if (i >= n8) return;
  const float* s = src + (size_t)i*8;
  h16x8 o;
  #pragma unroll
  for (int q=0;q<8;++q) o[q] = (_Float16)s[q];
  *(h16x8*)(dst + (size_t)i*8) = o;
}

__device__ __forceinline__ void split8r(const float* x, short8& vh, short8& vl){
  #pragma unroll
  for (int q=0;q<8;++q){ short h,l; splitbf(x[q],h,l); vh[q]=h; vl[q]=l; }
}

// ---------------- LSTM1: K-split 8-wave GEMM + cell update (R12-proven) ----------------
__global__ __launch_bounds__(512) void lstm1_k(
  const int* __restrict__ text, int t, int par,
  const float* __restrict__ emb,
  const float* __restrict__ ctx,
  float* __restrict__ h1b,
  float* __restrict__ c1,
  const u16* __restrict__ Whi, const u16* __restrict__ Wlo,
  const float* __restrict__ b_ih, const float* __restrict__ b_hh)
{
  __shared__ __align__(16) float accS[4][4][2][64][4];   // [gate][kq][nh][lane][reg] 32KB
  const float* h1_old = h1b + (size_t)par*NB*HH;
  float* h1_new = h1b + (size_t)(par^1)*NB*HH;
  int b = blockIdx.x;
  int jt  = (b&7)*4 + ((b>>3)&3);     // XCD-grouped jh tiles (W slice L2-resident)
  int jh0 = jt*16;
  int n0  = (b>>5)*32;
  int tid = threadIdx.x, w = tid>>6, l = tid&63;
  int nh = w&1, kq = w>>1;
  int kbase = kq*(K1/4);
  int col = l&15, kc = l>>4, ofs = kc*8;

  int arow = n0 + nh*16 + col;
  const float* aemb = emb + (size_t)text[arow*TLEN + t]*HH;
  const float* actx = ctx + (size_t)arow*DV;
  const float* ah1  = h1_old + (size_t)arow*HH;

  const u16* pBh[4]; const u16* pBl[4];
  #pragma unroll
  for (int g=0; g<4; ++g){
    size_t r = (size_t)(g*512 + jh0 + col)*K1 + kbase + ofs;
    pBh[g] = Whi + r; pBl[g] = Wlo + r;
  }

  f32x4 acc[4];
  #pragma unroll
  for (int g=0;g<4;++g) acc[g] = (f32x4){0.f,0.f,0.f,0.f};

  float xs[8]; short8 rbh[4], rbl[4];
  {
    int k = kbase;
    const float* src = (k<512)? (aemb+k) : (k<768)? (actx+(k-512)) : (ah1+(k-768));
    *(float4*)&xs[0] = *(const float4*)(src + ofs);
    *(float4*)&xs[4] = *(const float4*)(src + ofs + 4);
    #pragma unroll
    for (int g=0;g<4;++g){ rbh[g] = *(const short8*)(pBh[g]); rbl[g] = *(const short8*)(pBl[g]); }
  }

  for (int k0=0; k0<K1/4; k0+=32){
    float cxs[8];
    #pragma unroll
    for (int q=0;q<8;++q) cxs[q] = xs[q];
    short8 cbh[4], cbl[4];
    #pragma unroll
    for (int g=0;g<4;++g){ cbh[g]=rbh[g]; cbl[g]=rbl[g]; }
    int k0n = k0 + 32;
    if (k0n < K1/4){
      int k = kbase + k0n;
      const float* src = (k<512)? (aemb+k) : (k<768)? (actx+(k-512)) : (ah1+(k-768));
      *(float4*)&xs[0] = *(const float4*)(src + ofs);
      *(float4*)&xs[4] = *(const float4*)(src + ofs + 4);
      #pragma unroll
      for (int g=0;g<4;++g){ rbh[g] = *(const short8*)(pBh[g] + k0n); rbl[g] = *(const short8*)(pBl[g] + k0n); }
    }
    short8 avh, avl;
    split8r(cxs, avh, avl);
    #pragma unroll
    for (int g=0; g<4; ++g){
      acc[g] = __builtin_amdgcn_mfma_f32_16x16x32_bf16(avh, cbh[g], acc[g], 0,0,0);
      acc[g] = __builtin_amdgcn_mfma_f32_16x16x32_bf16(avl, cbh[g], acc[g], 0,0,0);
      acc[g] = __builtin_amdgcn_mfma_f32_16x16x32_bf16(avh, cbl[g], acc[g], 0,0,0);
    }
  }

  #pragma unroll
  for (int g=0;g<4;++g) *(f32x4*)&accS[g][kq][nh][l][0] = acc[g];
  __syncthreads();

  int en = tid>>4, ej = tid&15;
  int nhe = en>>4, r = en&15;
  int lane_e = ((r>>2)<<4) | ej, reg = r&3;
  float gv4[4];
  #pragma unroll
  for (int g=0;g<4;++g){
    gv4[g] = accS[g][0][nhe][lane_e][reg] + accS[g][1][nhe][lane_e][reg]
           + accS[g][2][nhe][lane_e][reg] + accS[g][3][nhe][lane_e][reg];
  }
  int jh = jh0 + ej;
  float bi  = b_ih[jh]      + b_hh[jh];
  float bff = b_ih[HH+jh]   + b_hh[HH+jh];
  float bg  = b_ih[2*HH+jh] + b_hh[2*HH+jh];
  float bo  = b_ih[3*HH+jh] + b_hh[3*HH+jh];
  size_t idx = (size_t)(n0+en)*HH + jh;
  float iv = sigm(gv4[0]+bi);
  float fv = sigm(gv4[1]+bff);
  float gg = tanhf(gv4[2]+bg);
  float ov = sigm(gv4[3]+bo);
  float cn = fv*c1[idx] + iv*gg;
  c1[idx] = cn;
  h1_new[idx] = ov*tanhf(cn);
}

// ---------------- LSTM2: K-split 8-wave, K=768 (R12-proven) ----------------
__global__ __launch_bounds__(512) void lstm2_k(
  int par,
  const float* __restrict__ h1b,
  float* __restrict__ h2b,
  float* __restrict__ c2,
  const u16* __restrict__ Whi, const u16* __restrict__ Wlo,
  const float* __restrict__ b_ih, const float* __restrict__ b_hh)
{
  __shared__ __align__(16) float accS[4][4][2][64][4];
  const float* h1_cur = h1b + (size_t)(par^1)*NB*HH;
  const float* h2_old = h2b + (size_t)par*NB*DK;
  float* h2_new = h2b + (size_t)(par^1)*NB*DK;
  int b = blockIdx.x;
  int jt  = (b&7)*2 + ((b>>3)&1);
  int jh0 = jt*16;
  int n0  = (b>>4)*32;
  int tid = threadIdx.x, w = tid>>6, l = tid&63;
  int nh = w&1, kq = w>>1;
  int kbase = kq*(K2/4);
  int col = l&15, kc = l>>4, ofs = kc*8;

  int arow = n0 + nh*16 + col;
  const float* ah1 = h1_cur + (size_t)arow*HH;
  const float* ah2 = h2_old + (size_t)arow*DK;

  const u16* pBh[4]; const u16* pBl[4];
  #pragma unroll
  for (int g=0; g<4; ++g){
    size_t r = (size_t)(g*256 + jh0 + col)*K2 + kbase + ofs;
    pBh[g] = Whi + r; pBl[g] = Wlo + r;
  }

  f32x4 acc[4];
  #pragma unroll
  for (int g=0;g<4;++g) acc[g] = (f32x4){0.f,0.f,0.f,0.f};

  float xs[8]; short8 rbh[4], rbl[4];
  {
    int k = kbase;
    const float* src = (k<512)? (ah1+k) : (ah2+(k-512));
    *(float4*)&xs[0] = *(const float4*)(src + ofs);
    *(float4*)&xs[4] = *(const float4*)(src + ofs + 4);
    #pragma unroll
    for (int g=0;g<4;++g){ rbh[g] = *(const short8*)(pBh[g]); rbl[g] = *(const short8*)(pBl[g]); }
  }

  for (int k0=0; k0<K2/4; k0+=32){
    float cxs[8];
    #pragma unroll
    for (int q=0;q<8;++q) cxs[q] = xs[q];
    short8 cbh[4], cbl[4];
    #pragma unroll
    for (int g=0;g<4;++g){ cbh[g]=rbh[g]; cbl[g]=rbl[g]; }
    int k0n = k0 + 32;
    if (k0n < K2/4){
      int k = kbase + k0n;
      const float* src = (k<512)? (ah1+k) : (ah2+(k-512));
      *(float4*)&xs[0] = *(const float4*)(src + ofs);
      *(float4*)&xs[4] = *(const float4*)(src + ofs + 4);
      #pragma unroll
      for (int g=0;g<4;++g){ rbh[g] = *(const short8*)(pBh[g] + k0n); rbl[g] = *(const short8*)(pBl[g] + k0n); }
    }
    short8 avh, avl;
    split8r(cxs, avh, avl);
    #pragma unroll
    for (int g=0; g<4; ++g){
      acc[g] = __builtin_amdgcn_mfma_f32_16x16x32_bf16(avh, cbh[g], acc[g], 0,0,0);
      acc[g] = __builtin_amdgcn_mfma_f32_16x16x32_bf16(avl, cbh[g], acc[g], 0,0,0);
      acc[g] = __builtin_amdgcn_mfma_f32_16x16x32_bf16(avh, cbl[g], acc[g], 0,0,0);
    }
  }

  #pragma unroll
  for (int g=0;g<4;++g) *(f32x4*)&accS[g][kq][nh][l][0] = acc[g];
  __syncthreads();

  int en = tid>>4, ej = tid&15;
  int nhe = en>>4, r = en&15;
  int lane_e = ((r>>2)<<4) | ej, reg = r&3;
  float gv4[4];
  #pragma unroll
  for (int g=0;g<4;++g){
    gv4[g] = accS[g][0][nhe][lane_e][reg] + accS[g][1][nhe][lane_e][reg]
           + accS[g][2][nhe][lane_e][reg] + accS[g][3][nhe][lane_e][reg];
  }
  int jh = jh0 + ej;
  float bi  = b_ih[jh]      + b_hh[jh];
  float bff = b_ih[DK+jh]   + b_hh[DK+jh];
  float bg  = b_ih[2*DK+jh] + b_hh[2*DK+jh];
  float bo  = b_ih[3*DK+jh] + b_hh[3*DK+jh];
  size_t idx = (size_t)(n0+en)*DK + jh;
  float iv = sigm(gv4[0]+bi);
  float fv = sigm(gv4[1]+bff);
  float gg = tanhf(gv4[2]+bg);
  float ov = sigm(gv4[3]+bo);
  float cn = fv*c2[idx] + iv*gg;
  c2[idx] = cn;
  h2_new[idx] = ov*tanhf(cn);
}

// ---------------- attention + softmax + ctx + output projection ----------------
// Template: F16 path reads f16 K/V copies (halved bytes, LLC-resident);
// f32 fallback identical to R12.
template<bool F16>
__global__ __launch_bounds__(512) void attn_k(
  const void* __restrict__ keysv, const void* __restrict__ valsv,
  const int* __restrict__ lens,
  const float* __restrict__ h2b, int par,
  float* __restrict__ ctx,
  const float* __restrict__ Wout, const float* __restrict__ b_out,
  float* __restrict__ out, int t)
{
  __shared__ float h2s[DK];
  __shared__ float e_s[TE];
  __shared__ float ctx_s[DV];
  __shared__ float ctxp[8][DV];
  __shared__ float red_s[16];
  int n = blockIdx.x, tid = threadIdx.x;
  int wv = tid>>6, lane = tid&63;
  const float* h2cur = h2b + (size_t)(par^1)*NB*DK;
  int L = lens[n] >> 3;
  if (tid < DK) h2s[tid] = h2cur[n*DK + tid];
  __syncthreads();
  float qreg[32];
  {
    int off = (lane&7)*32;
    #pragma unroll
    for (int q=0;q<32;q+=4){
      float4 v4 = *(const float4*)&h2s[off+q];
      qreg[q]=v4.x; qreg[q+1]=v4.y; qreg[q+2]=v4.z; qreg[q+3]=v4.w;
    }
  }
  // QK: 8 lanes/row, rows strided 64 across 8 waves
  for (int r = wv*8 + (lane>>3); r < L; r += 64){
    float s = 0.f;
    if (F16){
      const u16* kr = (const u16*)keysv + (size_t)(n*TE + r)*DK + (lane&7)*32;
      #pragma unroll
      for (int q=0;q<32;q+=8){
        h16x8 kv = *(const h16x8*)(kr + q);
        s += (float)kv[0]*qreg[q+0] + (float)kv[1]*qreg[q+1]
           + (float)kv[2]*qreg[q+2] + (float)kv[3]*qreg[q+3]
           + (float)kv[4]*qreg[q+4] + (float)kv[5]*qreg[q+5]
           + (float)kv[6]*qreg[q+6] + (float)kv[7]*qreg[q+7];
      }
    } else {
      const float* kr = (const float*)keysv + (size_t)(n*TE + r)*DK + (lane&7)*32;
      #pragma unroll
      for (int q=0;q<32;q+=4){
        float4 kv = *(const float4*)(kr + q);
        s += kv.x*qreg[q] + kv.y*qreg[q+1] + kv.z*qreg[q+2] + kv.w*qreg[q+3];
      }
    }
    s += __shfl_xor(s,1); s += __shfl_xor(s,2); s += __shfl_xor(s,4);
    if ((lane&7)==0) e_s[r] = s;
  }
  __syncthreads();
  float v = (tid < L) ? e_s[tid] : -1e30f;
  float m = v;
  #pragma unroll
  for (int o=1;o<64;o<<=1) m = fmaxf(m, __shfl_xor(m,o));
  if (lane==0) red_s[wv] = m;
  __syncthreads();
  m = red_s[0];
  #pragma unroll
  for (int q=1;q<8;++q) m = fmaxf(m, red_s[q]);
  float p = (tid < L) ? expf(v-m) : 0.f;
  float sm = p;
  #pragma unroll
  for (int o=1;o<64;o<<=1) sm += __shfl_xor(sm,o);
  if (lane==0) red_s[8+wv] = sm;
  __syncthreads();
  sm = red_s[8];
  #pragma unroll
  for (int q=1;q<8;++q) sm += red_s[8+q];
  e_s[tid] = p * (1.f/sm);
  __syncthreads();
  // PV: wave-strided rows; lane owns 4 v-dims
  float4 cacc = {0.f,0.f,0.f,0.f};
  if (F16){
    const u16* vpb = (const u16*)valsv + (size_t)n*TE*DV + lane*4;
    for (int r = wv; r < L; r += 8){
      float a = e_s[r];
      h16x4 vv = *(const h16x4*)(vpb + (size_t)r*DV);
      cacc.x += a*(float)vv[0]; cacc.y += a*(float)vv[1];
      cacc.z += a*(float)vv[2]; cacc.w += a*(float)vv[3];
    }
  } else {
    const float* vpb = (const float*)valsv + (size_t)n*TE*DV + lane*4;
    for (int r = wv; r < L; r += 8){
      float a = e_s[r];
      float4 vv4 = *(const float4*)(vpb + (size_t)r*DV);
      cacc.x += a*vv4.x; cacc.y += a*vv4.y; cacc.z += a*vv4.z; cacc.w += a*vv4.w;
    }
  }
  *(float4*)&ctxp[wv][lane*4] = cacc;
  __syncthreads();
  if (tid < DV){
    float cv = 0.f;
    #pragma unroll
    for (int q=0;q<8;++q) cv += ctxp[q][tid];
    ctx_s[tid] = cv;
    ctx[(size_t)n*DV + tid] = cv;
  }
  __syncthreads();
  #pragma unroll
  for (int vb2=0; vb2<2; ++vb2){
    int vvv = vb2*32 + (tid>>4);
    if (vvv < NV){
      int kbase = (tid&15)*32;
      float s = 0.f;
      #pragma unroll
      for (int q=0;q<32;q+=4){
        float4 w4 = *(const float4*)(Wout + (size_t)vvv*512 + kbase + q);
        int k = kbase + q;
        const float* xs = (k < DK)? &h2s[k] : &ctx_s[k-DK];
        s += w4.x*xs[0] + w4.y*xs[1] + w4.z*xs[2] + w4.w*xs[3];
      }
      s += __shfl_xor(s,1); s += __shfl_xor(s,2); s += __shfl_xor(s,4); s += __shfl_xor(s,8);
      if ((tid&15)==0) out[((size_t)n*STEPS + t)*NV + vvv] = s + b_out[vvv];
    }
  }
}

// ---------------- host ----------------
extern "C" void kernel_launch(void* const* d_in, const int* in_sizes, int n_in,
                              void* d_out, int out_size, void* d_ws, size_t ws_size,
                              hipStream_t stream)
{
  const float* enc_key = (const float*)d_in[0];
  const float* enc_val = (const float*)d_in[1];
  const int*   text    = (const int*)d_in[2];
  const int*   lens    = (const int*)d_in[3];
  const float* emb     = (const float*)d_in[5];
  const float* W_ih1   = (const float*)d_in[6];
  const float* W_hh1   = (const float*)d_in[7];
  const float* b_ih1   = (const float*)d_in[8];
  const float* b_hh1   = (const float*)d_in[9];
  const float* W_ih2   = (const float*)d_in[10];
  const float* W_hh2   = (const float*)d_in[11];
  const float* b_ih2   = (const float*)d_in[12];
  const float* b_hh2   = (const float*)d_in[13];
  const float* W_out   = (const float*)d_in[14];
  const float* b_out   = (const float*)d_in[15];
  float* out = (float*)d_out;

  char* ws = (char*)d_ws;
  size_t off = 0;
  auto alloc = [&](size_t bytes)->char*{
    char* p = ws + off; off = (off + bytes + 255) & ~(size_t)255; return p;
  };

  u16* Wc1h = (u16*)alloc((size_t)2048*K1*2);
  u16* Wc1l = (u16*)alloc((size_t)2048*K1*2);
  u16* Wc2h = (u16*)alloc((size_t)1024*K2*2);
  u16* Wc2l = (u16*)alloc((size_t)1024*K2*2);
  float* h1b = (float*)alloc((size_t)2*NB*HH*4);
  float* h2b = (float*)alloc((size_t)2*NB*DK*4);
  float* ctx = (float*)alloc((size_t)NB*DV*4);
  float* c1  = (float*)alloc((size_t)NB*HH*4);
  float* c2  = (float*)alloc((size_t)NB*DK*4);

  // zero recurrent state (contiguous block h1b..c2)
  size_t zbytes = (char*)c2 + (size_t)NB*DK*4 - (char*)h1b;
  (void)hipMemsetAsync(h1b, 0, zbytes, stream);

  // f16 K/V copies if workspace allows (halved attn bytes; LLC-resident)
  const size_t encElems = (size_t)NB*TE*DK;   // 33.5M each
  u16 *keyh = nullptr, *valh = nullptr;
  bool f16kv = (ws_size - off) >= (encElems*2*2 + 1024);
  if (f16kv){
    keyh = (u16*)alloc(encElems*2);
    valh = (u16*)alloc(encElems*2);
    int n8 = (int)(encElems/8);
    conv_f16<<<(n8+255)/256, 256, 0, stream>>>(keyh, enc_key, n8);
    conv_f16<<<(n8+255)/256, 256, 0, stream>>>(valh, enc_val, n8);
  }

  {
    int t8 = 2048*K1/8;
    conv_cat_split<<<(t8+255)/256, 256, 0, stream>>>(Wc1h, Wc1l, W_ih1, W_hh1, 768, 512, t8);
  }
  {
    int t8 = 1024*K2/8;
    conv_cat_split<<<(t8+255)/256, 256, 0, stream>>>(Wc2h, Wc2l, W_ih2, W_hh2, 512, 256, t8);
  }

  for (int t=0; t<STEPS; ++t){
    int par = t&1;
    lstm1_k<<<256, 512, 0, stream>>>(text, t, par, emb, ctx, h1b, c1, Wc1h, Wc1l, b_ih1, b_hh1);
    lstm2_k<<<128, 512, 0, stream>>>(par, h1b, h2b, c2, Wc2h, Wc2l, b_ih2, b_hh2);
    if (f16kv)
      attn_k<true><<<256, 512, 0, stream>>>(keyh, valh, lens, h2b, par, ctx, W_out, b_out, out, t);
    else
      attn_k<false><<<256, 512, 0, stream>>>(enc_key, enc_val, lens, h2b, par, ctx, W_out, b_out, out, t);
  }
}